// Round 3
// 693.142 us; speedup vs baseline: 1.0148x; 1.0148x over previous
//
#include <hip/hip_runtime.h>

#define KSEG   1024
#define CCH    128
#define HWPIX  (512 * 512)
#define BB     4
#define BLOCK  256

// v3: minimal diff from verified round-0 kernel. CG 8 -> 4 (LDS 32KB -> 16KB)
// + __launch_bounds__(256,8) => 8 blocks/CU, 32 waves/CU (was ~16).
// No workspace use (isolates the round-1/2 container failures).
#define CG     4
#define PIX_PER_BLOCK 16384           // 256 thr * 4 px * 16 iters
#define ITERS  (PIX_PER_BLOCK / (BLOCK * 4))    // 16
#define NXB    (HWPIX / PIX_PER_BLOCK)          // 16

// ord(-inf): 0xFF800000 ^ 0x7FFFFFFF
#define ORD_NEG_INF ((int)0x807FFFFF)

__device__ __forceinline__ int ord_f32(float f) {
    int i = __float_as_int(f);
    return i >= 0 ? i : (i ^ 0x7FFFFFFF);
}

__global__ __launch_bounds__(BLOCK) void init_kernel(int* __restrict__ out) {
    out[blockIdx.x * BLOCK + threadIdx.x] = ORD_NEG_INF;
}

__global__ __launch_bounds__(BLOCK) void decode_kernel(int* __restrict__ out) {
    const int idx = blockIdx.x * BLOCK + threadIdx.x;
    const int i = out[idx];
    ((float*)out)[idx] = __int_as_float(i >= 0 ? i : (i ^ 0x7FFFFFFF));
}

__global__ __launch_bounds__(BLOCK, 8) void pool_kernel(const float* __restrict__ img,
                                                        const int* __restrict__ spx,
                                                        int* __restrict__ out) {
    __shared__ int lmax[CG * KSEG];   // 16 KB -> 8 blocks/CU (VGPR-capped by launch_bounds)
    for (int i = threadIdx.x; i < CG * KSEG; i += BLOCK) lmax[i] = ORD_NEG_INF;
    __syncthreads();

    const int b  = blockIdx.z;
    const int c0 = blockIdx.y * CG;
    const int* __restrict__ spx_b = spx + b * HWPIX;
    const float* __restrict__ img_b = img + ((size_t)(b * CCH + c0)) * HWPIX;

    int p = blockIdx.x * PIX_PER_BLOCK + threadIdx.x * 4;
    for (int it = 0; it < ITERS; ++it, p += BLOCK * 4) {
        const int4 id = *(const int4*)(spx_b + p);
#pragma unroll
        for (int j = 0; j < CG; ++j) {
            const float4 v = *(const float4*)(img_b + (size_t)j * HWPIX + p);
            atomicMax(&lmax[j * KSEG + id.x], ord_f32(v.x));
            atomicMax(&lmax[j * KSEG + id.y], ord_f32(v.y));
            atomicMax(&lmax[j * KSEG + id.z], ord_f32(v.z));
            atomicMax(&lmax[j * KSEG + id.w], ord_f32(v.w));
        }
    }
    __syncthreads();

    for (int i = threadIdx.x; i < CG * KSEG; i += BLOCK) {
        const int j = i >> 10;              // channel within group
        const int k = i & (KSEG - 1);       // segment id
        atomicMax(&out[((size_t)(b * CCH + c0 + j)) * KSEG + k], lmax[i]);
    }
}

extern "C" void kernel_launch(void* const* d_in, const int* in_sizes, int n_in,
                              void* d_out, int out_size, void* d_ws, size_t ws_size,
                              hipStream_t stream) {
    const float* img = (const float*)d_in[0];
    const int*   spx = (const int*)d_in[1];
    int* out = (int*)d_out;   // ordered-int during accumulation

    // 1) init output bins to ord(-inf)  (out_size = 4*128*1024 = 524288)
    init_kernel<<<out_size / BLOCK, BLOCK, 0, stream>>>(out);

    // 2) LDS-privatized segment max, global int-atomic merge
    dim3 grid(NXB, CCH / CG, BB);   // (16, 32, 4) = 2048 blocks = 8/CU
    pool_kernel<<<grid, BLOCK, 0, stream>>>(img, spx, out);

    // 3) decode ordered ints back to floats in-place
    decode_kernel<<<out_size / BLOCK, BLOCK, 0, stream>>>(out);
}